// Round 1
// baseline (248.655 us; speedup 1.0000x reference)
//
#include <hip/hip_runtime.h>
#include <hip/hip_bf16.h>

// Problem: A=2048 assets, F=2048 flat dim.
//   q = z@Wq^T + bq ; k = z@Wk^T + bk ; v = z@Wv^T + bv
//   S = (q@k^T) * 1/8 ; P = softmax_rows(S) ; h = P@v
// All GEMMs expressed NT (A[m][k] . B[n][k]); v is produced transposed so PV is NT too.

#define AD 2048
#define FD 2048
constexpr float SM_SCALE = 0.125f;   // 64^-0.5

typedef __attribute__((ext_vector_type(8))) short bf16x8;
typedef __attribute__((ext_vector_type(4))) float f32x4;

constexpr int BM = 128, BN = 128, BK = 32;
constexpr int LSTR = BK + 8;   // padded LDS row stride (40 elems = 80B) -> conflict-free b128 reads

struct GemmArgs {
  const void* A;
  const void* B[3];
  const float* bias[3];
  void* out[3];
  int outmode[3];     // 0 = f32 row-major, 1 = bf16 row-major, 2 = bf16 transposed (store C^T)
  float scale;
};

__device__ __forceinline__ unsigned short f2bf(float f) {
  union { float f; unsigned u; } x; x.f = f;
  unsigned r = x.u + 0x7fffu + ((x.u >> 16) & 1u);   // round-to-nearest-even
  return (unsigned short)(r >> 16);
}

// stage 8 elements (one thread's slice) into LDS as bf16, single 16B ds_write
__device__ __forceinline__ void stage8(const float* __restrict__ src, __hip_bfloat16* dst) {
  const float4 a = *reinterpret_cast<const float4*>(src);
  const float4 b = *reinterpret_cast<const float4*>(src + 4);
  union { unsigned short us[8]; int4 v; } pk;
  pk.us[0] = f2bf(a.x); pk.us[1] = f2bf(a.y); pk.us[2] = f2bf(a.z); pk.us[3] = f2bf(a.w);
  pk.us[4] = f2bf(b.x); pk.us[5] = f2bf(b.y); pk.us[6] = f2bf(b.z); pk.us[7] = f2bf(b.w);
  *reinterpret_cast<int4*>(dst) = pk.v;
}
__device__ __forceinline__ void stage8(const __hip_bfloat16* __restrict__ src, __hip_bfloat16* dst) {
  *reinterpret_cast<int4*>(dst) = *reinterpret_cast<const int4*>(src);
}

template<typename TIN>
__global__ __launch_bounds__(256) void gemm_nt(GemmArgs args) {
  __shared__ __hip_bfloat16 ldsA[BM * LSTR];
  __shared__ __hip_bfloat16 ldsB[BN * LSTR];

  const int z = blockIdx.z;
  const TIN* __restrict__ A = (const TIN*)args.A;
  const TIN* __restrict__ B = (const TIN*)args.B[z];
  const float* __restrict__ bias = args.bias[z];

  const int tid  = threadIdx.x;
  const int bn   = blockIdx.x, bm = blockIdx.y;
  const int lane = tid & 63;
  const int wave = tid >> 6;
  const int wr   = wave >> 1, wc = wave & 1;   // 2x2 waves, 64x64 each

  const int srow = tid >> 2;          // 0..63   (staging row)
  const int scol = (tid & 3) * 8;     // 0,8,16,24

  const TIN* aptr = A + (size_t)(bm * BM + srow) * FD + scol;
  const TIN* bptr = B + (size_t)(bn * BN + srow) * FD + scol;
  const int aoff0 = srow * LSTR + scol;

  f32x4 acc[4][4] = {};

  for (int k0 = 0; k0 < FD; k0 += BK) {
    stage8(aptr + k0,                 &ldsA[aoff0]);
    stage8(aptr + (size_t)64*FD + k0, &ldsA[aoff0 + 64 * LSTR]);
    stage8(bptr + k0,                 &ldsB[aoff0]);
    stage8(bptr + (size_t)64*FD + k0, &ldsB[aoff0 + 64 * LSTR]);
    __syncthreads();

    const int koff = (lane >> 4) * 8;
    const int fr   = lane & 15;
    bf16x8 af[4], bfr[4];
    #pragma unroll
    for (int m = 0; m < 4; ++m)
      af[m] = *reinterpret_cast<const bf16x8*>(&ldsA[(wr*64 + m*16 + fr) * LSTR + koff]);
    #pragma unroll
    for (int n = 0; n < 4; ++n)
      bfr[n] = *reinterpret_cast<const bf16x8*>(&ldsB[(wc*64 + n*16 + fr) * LSTR + koff]);
    #pragma unroll
    for (int m = 0; m < 4; ++m)
      #pragma unroll
      for (int n = 0; n < 4; ++n)
        acc[m][n] = __builtin_amdgcn_mfma_f32_16x16x32_bf16(af[m], bfr[n], acc[m][n], 0, 0, 0);
    __syncthreads();
  }

  // epilogue: D[row][col], col = lane&15, row = (lane>>4)*4 + j  (m89-verified mapping)
  const float scale = args.scale;
  const int outmode = args.outmode[z];
  const int row0 = bm * BM + wr * 64 + (lane >> 4) * 4;
  const int col0 = bn * BN + wc * 64 + (lane & 15);

  if (outmode == 0) {
    float* __restrict__ out = (float*)args.out[z];
    #pragma unroll
    for (int m = 0; m < 4; ++m)
      #pragma unroll
      for (int n = 0; n < 4; ++n) {
        const int cg = col0 + n * 16;
        const float badd = bias ? bias[cg] : 0.f;
        #pragma unroll
        for (int j = 0; j < 4; ++j)
          out[(size_t)(row0 + m*16 + j) * FD + cg] = acc[m][n][j] * scale + badd;
      }
  } else if (outmode == 1) {
    __hip_bfloat16* __restrict__ out = (__hip_bfloat16*)args.out[z];
    #pragma unroll
    for (int m = 0; m < 4; ++m)
      #pragma unroll
      for (int n = 0; n < 4; ++n) {
        const int cg = col0 + n * 16;
        const float badd = bias ? bias[cg] : 0.f;
        #pragma unroll
        for (int j = 0; j < 4; ++j) {
          unsigned short b16 = f2bf(acc[m][n][j] * scale + badd);
          out[(size_t)(row0 + m*16 + j) * FD + cg] = *reinterpret_cast<__hip_bfloat16*>(&b16);
        }
      }
  } else { // outmode == 2: store C^T (for v -> v^T), 4 consecutive rows pack to one 8B store
    __hip_bfloat16* __restrict__ out = (__hip_bfloat16*)args.out[z];
    #pragma unroll
    for (int m = 0; m < 4; ++m)
      #pragma unroll
      for (int n = 0; n < 4; ++n) {
        const int cg = col0 + n * 16;           // logical col (F dim) -> row of v^T
        const int rg = row0 + m * 16;           // logical row (asset) -> col of v^T
        const float badd = bias ? bias[cg] : 0.f;
        ushort4 pk;
        pk.x = f2bf(acc[m][n][0] * scale + badd);
        pk.y = f2bf(acc[m][n][1] * scale + badd);
        pk.z = f2bf(acc[m][n][2] * scale + badd);
        pk.w = f2bf(acc[m][n][3] * scale + badd);
        *reinterpret_cast<ushort4*>(out + (size_t)cg * AD + rg) = pk;
      }
  }
}

__global__ __launch_bounds__(256) void softmax_rows(const float* __restrict__ S,
                                                    __hip_bfloat16* __restrict__ P) {
  const int row = blockIdx.x;
  const int t = threadIdx.x;
  const float* s = S + (size_t)row * AD + t * 8;
  const float4 v0 = *reinterpret_cast<const float4*>(s);
  const float4 v1 = *reinterpret_cast<const float4*>(s + 4);
  float vals[8] = {v0.x, v0.y, v0.z, v0.w, v1.x, v1.y, v1.z, v1.w};

  float m = vals[0];
  #pragma unroll
  for (int j = 1; j < 8; ++j) m = fmaxf(m, vals[j]);
  #pragma unroll
  for (int off = 32; off >= 1; off >>= 1) m = fmaxf(m, __shfl_xor(m, off));

  __shared__ float redm[4], reds[4];
  if ((t & 63) == 0) redm[t >> 6] = m;
  __syncthreads();
  m = fmaxf(fmaxf(redm[0], redm[1]), fmaxf(redm[2], redm[3]));

  float e[8];
  float sum = 0.f;
  #pragma unroll
  for (int j = 0; j < 8; ++j) { e[j] = __expf(vals[j] - m); sum += e[j]; }
  #pragma unroll
  for (int off = 32; off >= 1; off >>= 1) sum += __shfl_xor(sum, off);
  if ((t & 63) == 0) reds[t >> 6] = sum;
  __syncthreads();
  sum = reds[0] + reds[1] + reds[2] + reds[3];
  const float inv = 1.f / sum;

  union { unsigned short us[8]; int4 v; } pk;
  #pragma unroll
  for (int j = 0; j < 8; ++j) pk.us[j] = f2bf(e[j] * inv);
  *reinterpret_cast<int4*>(P + (size_t)row * AD + t * 8) = pk.v;
}

extern "C" void kernel_launch(void* const* d_in, const int* in_sizes, int n_in,
                              void* d_out, int out_size, void* d_ws, size_t ws_size,
                              hipStream_t stream) {
  const float* z  = (const float*)d_in[0];
  const float* Wq = (const float*)d_in[1];
  const float* bq = (const float*)d_in[2];
  const float* Wk = (const float*)d_in[3];
  const float* bk = (const float*)d_in[4];
  const float* Wv = (const float*)d_in[5];
  const float* bv = (const float*)d_in[6];

  char* ws = (char*)d_ws;
  const size_t MB8 = (size_t)8 * 1024 * 1024;
  __hip_bfloat16* qb = (__hip_bfloat16*)(ws);             // 2048x2048 bf16
  __hip_bfloat16* kb = (__hip_bfloat16*)(ws + MB8);       // 2048x2048 bf16
  __hip_bfloat16* vT = (__hip_bfloat16*)(ws + 2 * MB8);   // 2048x2048 bf16 (F x A)
  __hip_bfloat16* pb = (__hip_bfloat16*)(ws + 3 * MB8);   // attn 2048x2048 bf16

  // 1) fused QKV: z(f32) @ W^T + b -> q,k bf16 row-major ; v bf16 transposed
  {
    GemmArgs a;
    a.A = z;
    a.B[0] = Wq; a.B[1] = Wk; a.B[2] = Wv;
    a.bias[0] = bq; a.bias[1] = bk; a.bias[2] = bv;
    a.out[0] = qb; a.out[1] = kb; a.out[2] = vT;
    a.outmode[0] = 1; a.outmode[1] = 1; a.outmode[2] = 2;
    a.scale = 1.0f;
    gemm_nt<float><<<dim3(AD / BN, AD / BM, 3), dim3(256), 0, stream>>>(a);
  }
  // 2) scores = (q @ k^T) * SCALE -> f32 into d_out (used as scratch; fully overwritten later)
  {
    GemmArgs a;
    a.A = qb;
    a.B[0] = a.B[1] = a.B[2] = kb;
    a.bias[0] = a.bias[1] = a.bias[2] = nullptr;
    a.out[0] = a.out[1] = a.out[2] = d_out;
    a.outmode[0] = a.outmode[1] = a.outmode[2] = 0;
    a.scale = SM_SCALE;
    gemm_nt<__hip_bfloat16><<<dim3(AD / BN, AD / BM, 1), dim3(256), 0, stream>>>(a);
  }
  // 3) row softmax -> bf16 attn
  softmax_rows<<<dim3(AD), dim3(256), 0, stream>>>((const float*)d_out, pb);
  // 4) h = attn @ v = attn @ (vT)^T -> f32 d_out
  {
    GemmArgs a;
    a.A = pb;
    a.B[0] = a.B[1] = a.B[2] = vT;
    a.bias[0] = a.bias[1] = a.bias[2] = nullptr;
    a.out[0] = a.out[1] = a.out[2] = d_out;
    a.outmode[0] = a.outmode[1] = a.outmode[2] = 0;
    a.scale = 1.0f;
    gemm_nt<__hip_bfloat16><<<dim3(AD / BN, AD / BM, 1), dim3(256), 0, stream>>>(a);
  }
}

// Round 3
// 191.432 us; speedup vs baseline: 1.2989x; 1.2989x over previous
//
#include <hip/hip_runtime.h>
#include <hip/hip_bf16.h>

// A=2048 assets, F=2048 flat dim.
//   q = z@Wq^T + bq ; k = z@Wk^T + bk ; v = z@Wv^T + bv
//   S = (q@k^T)/8 ; P = softmax_rows(S) ; h = P@v
// All GEMMs NT (A[m][k] . B[n][k]), bf16 inputs via pre-convert, f32 accum.
// v stored transposed (vT) so PV is NT too.
//
// ws layout (32 MB total), liveness-based reuse:
//   [0:8MB)   Wqb  -> after QK: vT
//   [8:16MB)  zb   -> after V:  S (f32, spans 8..24MB)
//   [16:24MB) Wkb  ->           S cont'd
//   [24:32MB) Wvb  -> after V:  P (bf16)
//   d_out: qb(0:8MB)+kb(8:16MB) bf16 -> after scores read: h f32 (final)

#define AD 2048
#define FD 2048
constexpr float SM_SCALE = 0.125f;   // 64^-0.5

typedef __attribute__((ext_vector_type(8))) short bf16x8;
typedef __attribute__((ext_vector_type(4))) float f32x4;

constexpr int BM = 128, BN = 128, BK = 32;
constexpr int MREP = 2, NREP = 4;       // per-wave: 32x64 output, 8 waves (4x2)
constexpr int NT = 512;

__device__ __forceinline__ unsigned short f2bf(float f) {
  union { float f; unsigned u; } x; x.f = f;
  unsigned r = x.u + 0x7fffu + ((x.u >> 16) & 1u);   // RNE
  return (unsigned short)(r >> 16);
}

typedef __attribute__((address_space(1))) const void GVOID;
typedef __attribute__((address_space(3))) void LVOID;

__device__ __forceinline__ void gload16(const void* g, void* l) {
  __builtin_amdgcn_global_load_lds((GVOID*)g, (LVOID*)l, 16, 0, 0);
}

struct GemmArgs {
  const void* A;
  const void* B[2];
  const float* bias[2];
  void* out[2];
  float scale;
};

// OUTMODE: 0 = f32 row-major (scale, no bias), 1 = bf16 row-major (+bias),
//          2 = bf16 transposed C^T (+bias)
template<int OUTMODE>
__global__ __launch_bounds__(NT, 2) void gemm8w(GemmArgs args) {
  __shared__ __hip_bfloat16 lA[BM * BK];
  __shared__ __hip_bfloat16 lB[BN * BK];

  const int z = blockIdx.z;
  const __hip_bfloat16* __restrict__ A = (const __hip_bfloat16*)args.A;
  const __hip_bfloat16* __restrict__ B = (const __hip_bfloat16*)args.B[z];

  const int t    = threadIdx.x;
  const int bn   = blockIdx.x, bm = blockIdx.y;
  const int lane = t & 63;
  const int wv   = t >> 6;          // 0..7
  const int wr   = wv >> 1;         // 0..3 (rows, 32 each)
  const int wc   = wv & 1;          // 0..1 (cols, 64 each)

  // staging: thread t owns bytes [t*16, t*16+16) of each 8KB tile (linear LDS)
  const int srow = t >> 2;          // 0..127
  const int sce  = (t & 3) * 8;     // elem col 0,8,16,24
  const __hip_bfloat16* ga = A + (size_t)(bm * BM + srow) * FD + sce;
  const __hip_bfloat16* gb = B + (size_t)(bn * BN + srow) * FD + sce;
  __hip_bfloat16* la = &lA[t * 8];
  __hip_bfloat16* lb = &lB[t * 8];

  const int fr = lane & 15;
  const int ko = (lane >> 4) * 8;

  f32x4 acc[MREP][NREP] = {};

  for (int k0 = 0; k0 < FD; k0 += BK) {
    gload16(ga + k0, la);
    gload16(gb + k0, lb);
    __syncthreads();   // compiler drains vmcnt before barrier -> LDS ready

    bf16x8 af[MREP], bfr[NREP];
    #pragma unroll
    for (int m = 0; m < MREP; ++m)
      af[m] = *reinterpret_cast<const bf16x8*>(&lA[(wr * (MREP*16) + m*16 + fr) * BK + ko]);
    #pragma unroll
    for (int n = 0; n < NREP; ++n)
      bfr[n] = *reinterpret_cast<const bf16x8*>(&lB[(wc * (NREP*16) + n*16 + fr) * BK + ko]);
    #pragma unroll
    for (int m = 0; m < MREP; ++m)
      #pragma unroll
      for (int n = 0; n < NREP; ++n)
        acc[m][n] = __builtin_amdgcn_mfma_f32_16x16x32_bf16(af[m], bfr[n], acc[m][n], 0, 0, 0);
    __syncthreads();   // all frag reads done before next stage overwrites
  }

  // C/D mapping (m89-verified): col = lane&15, row = (lane>>4)*4 + j
  const float scale = args.scale;
  const float* __restrict__ bias = args.bias[z];
  const int row0 = bm * BM + wr * (MREP*16) + (lane >> 4) * 4;
  const int col0 = bn * BN + wc * (NREP*16) + fr;

  if (OUTMODE == 0) {
    float* __restrict__ out = (float*)args.out[z];
    #pragma unroll
    for (int m = 0; m < MREP; ++m)
      #pragma unroll
      for (int n = 0; n < NREP; ++n) {
        const int cg = col0 + n * 16;
        #pragma unroll
        for (int j = 0; j < 4; ++j)
          out[(size_t)(row0 + m*16 + j) * FD + cg] = acc[m][n][j] * scale;
      }
  } else if (OUTMODE == 1) {
    __hip_bfloat16* __restrict__ out = (__hip_bfloat16*)args.out[z];
    #pragma unroll
    for (int m = 0; m < MREP; ++m)
      #pragma unroll
      for (int n = 0; n < NREP; ++n) {
        const int cg = col0 + n * 16;
        const float badd = bias[cg];
        #pragma unroll
        for (int j = 0; j < 4; ++j) {
          unsigned short b16 = f2bf(acc[m][n][j] + badd);
          out[(size_t)(row0 + m*16 + j) * FD + cg] = *reinterpret_cast<__hip_bfloat16*>(&b16);
        }
      }
  } else { // OUTMODE == 2: store C^T -> vT[f][a]; 4 consecutive rows = 8B store
    __hip_bfloat16* __restrict__ out = (__hip_bfloat16*)args.out[z];
    #pragma unroll
    for (int m = 0; m < MREP; ++m)
      #pragma unroll
      for (int n = 0; n < NREP; ++n) {
        const int cg = col0 + n * 16;   // F index -> row of vT
        const int rg = row0 + m * 16;   // asset index -> col of vT
        const float badd = bias[cg];
        ushort4 pk;
        pk.x = f2bf(acc[m][n][0] + badd);
        pk.y = f2bf(acc[m][n][1] + badd);
        pk.z = f2bf(acc[m][n][2] + badd);
        pk.w = f2bf(acc[m][n][3] + badd);
        *reinterpret_cast<ushort4*>(out + (size_t)cg * AD + rg) = pk;
      }
  }
}

// convert z, Wq, Wk, Wv (f32) -> bf16 into ws: [Wqb | zb | Wkb | Wvb], 4M elems each
__global__ __launch_bounds__(256) void cvt_bf16(const float* __restrict__ z,
                                                const float* __restrict__ wq,
                                                const float* __restrict__ wk,
                                                const float* __restrict__ wv,
                                                __hip_bfloat16* __restrict__ dst) {
  const size_t NITEM = (size_t)4 * 4096 * 1024 / 8;   // 16M elems / 8 = 2M items
  const size_t step = (size_t)gridDim.x * blockDim.x;
  for (size_t idx = (size_t)blockIdx.x * blockDim.x + threadIdx.x; idx < NITEM; idx += step) {
    const int ten = (int)(idx >> 19);                 // 512K items per tensor
    const size_t off = (idx & ((1u << 19) - 1)) * 8;
    const float* src = (ten == 0) ? wq : (ten == 1) ? z : (ten == 2) ? wk : wv;
    const float4 a = *reinterpret_cast<const float4*>(src + off);
    const float4 b = *reinterpret_cast<const float4*>(src + off + 4);
    union { unsigned short us[8]; int4 v; } pk;
    pk.us[0] = f2bf(a.x); pk.us[1] = f2bf(a.y); pk.us[2] = f2bf(a.z); pk.us[3] = f2bf(a.w);
    pk.us[4] = f2bf(b.x); pk.us[5] = f2bf(b.y); pk.us[6] = f2bf(b.z); pk.us[7] = f2bf(b.w);
    *reinterpret_cast<int4*>(dst + (size_t)ten * 4096 * 1024 + off) = pk.v;
  }
}

__global__ __launch_bounds__(256) void softmax_rows(const float* __restrict__ S,
                                                    __hip_bfloat16* __restrict__ P) {
  const int row = blockIdx.x;
  const int t = threadIdx.x;
  const float* s = S + (size_t)row * AD + t * 8;
  const float4 v0 = *reinterpret_cast<const float4*>(s);
  const float4 v1 = *reinterpret_cast<const float4*>(s + 4);
  float vals[8] = {v0.x, v0.y, v0.z, v0.w, v1.x, v1.y, v1.z, v1.w};

  float m = vals[0];
  #pragma unroll
  for (int j = 1; j < 8; ++j) m = fmaxf(m, vals[j]);
  #pragma unroll
  for (int off = 32; off >= 1; off >>= 1) m = fmaxf(m, __shfl_xor(m, off));

  __shared__ float redm[4], reds[4];
  if ((t & 63) == 0) redm[t >> 6] = m;
  __syncthreads();
  m = fmaxf(fmaxf(redm[0], redm[1]), fmaxf(redm[2], redm[3]));

  float e[8];
  float sum = 0.f;
  #pragma unroll
  for (int j = 0; j < 8; ++j) { e[j] = __expf(vals[j] - m); sum += e[j]; }
  #pragma unroll
  for (int off = 32; off >= 1; off >>= 1) sum += __shfl_xor(sum, off);
  if ((t & 63) == 0) reds[t >> 6] = sum;
  __syncthreads();
  sum = reds[0] + reds[1] + reds[2] + reds[3];
  const float inv = 1.f / sum;

  union { unsigned short us[8]; int4 v; } pk;
  #pragma unroll
  for (int j = 0; j < 8; ++j) pk.us[j] = f2bf(e[j] * inv);
  *reinterpret_cast<int4*>(P + (size_t)row * AD + t * 8) = pk.v;
}

extern "C" void kernel_launch(void* const* d_in, const int* in_sizes, int n_in,
                              void* d_out, int out_size, void* d_ws, size_t ws_size,
                              hipStream_t stream) {
  const float* z  = (const float*)d_in[0];
  const float* Wq = (const float*)d_in[1];
  const float* bq = (const float*)d_in[2];
  const float* Wk = (const float*)d_in[3];
  const float* bk = (const float*)d_in[4];
  const float* Wv = (const float*)d_in[5];
  const float* bv = (const float*)d_in[6];

  char* ws = (char*)d_ws;
  const size_t MB8 = (size_t)8 * 1024 * 1024;
  __hip_bfloat16* Wqb = (__hip_bfloat16*)(ws);            // dies after QK
  __hip_bfloat16* zb  = (__hip_bfloat16*)(ws + MB8);      // dies after V
  __hip_bfloat16* Wkb = (__hip_bfloat16*)(ws + 2*MB8);    // dies after QK
  __hip_bfloat16* Wvb = (__hip_bfloat16*)(ws + 3*MB8);    // dies after V
  __hip_bfloat16* vT  = (__hip_bfloat16*)(ws);            // over Wqb
  float*          S   = (float*)(ws + MB8);               // over zb+Wkb (16MB)
  __hip_bfloat16* P   = (__hip_bfloat16*)(ws + 3*MB8);    // over Wvb
  __hip_bfloat16* qb  = (__hip_bfloat16*)d_out;           // d_out as scratch (8MB)
  __hip_bfloat16* kb  = (__hip_bfloat16*)d_out + (size_t)AD * FD;  // FIX: +4M elems = +8MB

  // 0) convert inputs to bf16
  cvt_bf16<<<dim3(2048), dim3(256), 0, stream>>>(z, Wq, Wk, Wv, (__hip_bfloat16*)ws);

  // 1) fused Q,K: zb @ W^T + b -> bf16 into d_out   (512 blocks, ~2/CU)
  {
    GemmArgs a;
    a.A = zb;
    a.B[0] = Wqb;  a.B[1] = Wkb;
    a.bias[0] = bq; a.bias[1] = bk;
    a.out[0] = qb;  a.out[1] = kb;
    a.scale = 1.0f;
    gemm8w<1><<<dim3(AD/BN, AD/BM, 2), dim3(NT), 0, stream>>>(a);
  }
  // 2) V: zb @ Wv^T + bv -> vT (bf16, transposed) over Wqb
  {
    GemmArgs a;
    a.A = zb;
    a.B[0] = a.B[1] = Wvb;
    a.bias[0] = a.bias[1] = bv;
    a.out[0] = a.out[1] = vT;
    a.scale = 1.0f;
    gemm8w<2><<<dim3(AD/BN, AD/BM, 1), dim3(NT), 0, stream>>>(a);
  }
  // 3) scores = (qb @ kb^T) * SCALE -> f32 S (over zb/Wkb)
  {
    GemmArgs a;
    a.A = qb;
    a.B[0] = a.B[1] = kb;
    a.bias[0] = a.bias[1] = nullptr;
    a.out[0] = a.out[1] = S;
    a.scale = SM_SCALE;
    gemm8w<0><<<dim3(AD/BN, AD/BM, 1), dim3(NT), 0, stream>>>(a);
  }
  // 4) softmax rows -> P bf16 (over Wvb)
  softmax_rows<<<dim3(AD), dim3(256), 0, stream>>>(S, P);
  // 5) h = P @ vT^T -> f32 d_out (over qb/kb)
  {
    GemmArgs a;
    a.A = P;
    a.B[0] = a.B[1] = vT;
    a.bias[0] = a.bias[1] = nullptr;
    a.out[0] = a.out[1] = d_out;
    a.scale = 1.0f;
    gemm8w<0><<<dim3(AD/BN, AD/BM, 1), dim3(NT), 0, stream>>>(a);
  }
}

// Round 4
// 165.377 us; speedup vs baseline: 1.5036x; 1.1576x over previous
//
#include <hip/hip_runtime.h>
#include <hip/hip_bf16.h>

// A=2048 assets, F=2048 flat dim.
//   q = z@Wq^T + bq ; k = z@Wk^T + bk ; v = z@Wv^T + bv
//   S = (q@k^T)/8 ; P = softmax_rows(S) ; h = P@v
// All GEMMs NT (A[m][k] . B[n][k]) on bf16 MFMA, f32 accum.
// v is produced transposed (vT) so PV is NT too.
//
// ws layout (32 MB), liveness:
//   [0:8)MB   zb   -> after QKV: S (f32, spans 0..16MB)
//   [8:16)MB  Wqb  ->           S cont'd
//   [16:24)MB Wkb  -> after softmax's producer (scores): P (bf16)
//   [24:32)MB vT   (written by QKV z=2; live until PV)
//   d_out: qb[0:8)MB + kb[8:16)MB bf16 -> overwritten by final h (f32) in PV.
// Wv is consumed f32 directly (reg-stage+cvt on B side of z=2 blocks only).

#define AD 2048
#define FD 2048
constexpr float SM_SCALE = 0.125f;   // 64^-0.5

typedef __attribute__((ext_vector_type(8))) short bf16x8;
typedef __attribute__((ext_vector_type(4))) float f32x4;

__device__ __forceinline__ unsigned short f2bf(float f) {
  union { float f; unsigned u; } x; x.f = f;
  unsigned r = x.u + 0x7fffu + ((x.u >> 16) & 1u);   // RNE
  return (unsigned short)(r >> 16);
}

typedef __attribute__((address_space(1))) const void GVOID;
typedef __attribute__((address_space(3))) void LVOID;

__device__ __forceinline__ void gload16(const void* g, void* l) {
  __builtin_amdgcn_global_load_lds((GVOID*)g, (LVOID*)l, 16, 0, 0);
}

struct GemmArgs {
  const void* A;
  const void* B[3];
  const float* bias[3];
  void* out[3];
  int outmode[3];   // 0 = f32 row-major (xscale), 1 = bf16 row-major (+bias), 2 = bf16 C^T (+bias)
  int bf32mask;     // bit z: B[z] is f32 (reg-stage + cvt)
  float scale;
};

// BM=128 fixed, BK=32 fixed. BN = NREP*32. 512 threads = 8 waves (4 row x 2 col),
// wave tile = 32 x (NREP*16). FORCE_MODE >= 0 compiles a single epilogue.
template<int NREP, int FORCE_MODE, bool MIXEDB>
__global__ __launch_bounds__(512, 2) void gemm_k(GemmArgs args) {
  constexpr int BN_ = NREP * 32;
  __shared__ __hip_bfloat16 lA[128 * 32];
  __shared__ __hip_bfloat16 lB[BN_ * 32];

  const int z = blockIdx.z;
  const __hip_bfloat16* __restrict__ A = (const __hip_bfloat16*)args.A;

  const int t    = threadIdx.x;
  const int bn   = blockIdx.x, bm = blockIdx.y;
  const int lane = t & 63;
  const int wv   = t >> 6;
  const int wr   = wv >> 1;        // 0..3, 32 rows each
  const int wc   = wv & 1;         // 0..1, NREP*16 cols each

  const int srow = t >> 2;         // staging row (A: 0..127; B uses t < BN_*4)
  const int sce  = (t & 3) * 8;    // staging elem col
  const bool bstage = (BN_ == 128) || (t < BN_ * 4);

  const __hip_bfloat16* ga = A + (size_t)(bm * 128 + srow) * FD + sce;
  const __hip_bfloat16* gb = (const __hip_bfloat16*)args.B[z] + (size_t)(bn * BN_ + srow) * FD + sce;
  const float*          gf = (const float*)args.B[z] + (size_t)(bn * BN_ + srow) * FD + sce;

  bool dof32 = false;
  if constexpr (MIXEDB) dof32 = (args.bf32mask >> z) & 1;

  const int fr = lane & 15;
  const int ko = (lane >> 4) * 8;

  f32x4 acc[2][NREP] = {};

  for (int k0 = 0; k0 < FD; k0 += 32) {
    gload16(ga + k0, &lA[t * 8]);
    if constexpr (MIXEDB) {
      if (dof32) {
        if (bstage) {
          const float4 x = *reinterpret_cast<const float4*>(gf + k0);
          const float4 y = *reinterpret_cast<const float4*>(gf + k0 + 4);
          union { unsigned short us[8]; int4 v; } pk;
          pk.us[0] = f2bf(x.x); pk.us[1] = f2bf(x.y); pk.us[2] = f2bf(x.z); pk.us[3] = f2bf(x.w);
          pk.us[4] = f2bf(y.x); pk.us[5] = f2bf(y.y); pk.us[6] = f2bf(y.z); pk.us[7] = f2bf(y.w);
          *reinterpret_cast<int4*>(&lB[t * 8]) = pk.v;
        }
      } else {
        if (bstage) gload16(gb + k0, &lB[t * 8]);
      }
    } else {
      if (bstage) gload16(gb + k0, &lB[t * 8]);
    }
    __syncthreads();

    bf16x8 af[2], bfr[NREP];
    #pragma unroll
    for (int m = 0; m < 2; ++m)
      af[m] = *reinterpret_cast<const bf16x8*>(&lA[(wr * 32 + m * 16 + fr) * 32 + ko]);
    #pragma unroll
    for (int n = 0; n < NREP; ++n)
      bfr[n] = *reinterpret_cast<const bf16x8*>(&lB[(wc * (NREP * 16) + n * 16 + fr) * 32 + ko]);
    #pragma unroll
    for (int m = 0; m < 2; ++m)
      #pragma unroll
      for (int n = 0; n < NREP; ++n)
        acc[m][n] = __builtin_amdgcn_mfma_f32_16x16x32_bf16(af[m], bfr[n], acc[m][n], 0, 0, 0);
    __syncthreads();
  }

  // C/D mapping (m89-verified): col = lane&15, row = (lane>>4)*4 + j
  const float scale = args.scale;
  const float* __restrict__ bias = args.bias[z];
  const int mode = (FORCE_MODE >= 0) ? FORCE_MODE : args.outmode[z];
  const int row0 = bm * 128 + wr * 32 + (lane >> 4) * 4;
  const int col0 = bn * BN_ + wc * (NREP * 16) + fr;

  if (mode == 0) {
    float* __restrict__ out = (float*)args.out[z];
    #pragma unroll
    for (int m = 0; m < 2; ++m)
      #pragma unroll
      for (int n = 0; n < NREP; ++n) {
        const int cg = col0 + n * 16;
        #pragma unroll
        for (int j = 0; j < 4; ++j)
          out[(size_t)(row0 + m * 16 + j) * FD + cg] = acc[m][n][j] * scale;
      }
  } else if (mode == 1) {
    __hip_bfloat16* __restrict__ out = (__hip_bfloat16*)args.out[z];
    #pragma unroll
    for (int m = 0; m < 2; ++m)
      #pragma unroll
      for (int n = 0; n < NREP; ++n) {
        const int cg = col0 + n * 16;
        const float badd = bias[cg];
        #pragma unroll
        for (int j = 0; j < 4; ++j) {
          unsigned short b16 = f2bf(acc[m][n][j] + badd);
          out[(size_t)(row0 + m * 16 + j) * FD + cg] = *reinterpret_cast<__hip_bfloat16*>(&b16);
        }
      }
  } else { // mode == 2: store C^T -> vT[f][a]; 4 consecutive rows pack to one 8B store
    __hip_bfloat16* __restrict__ out = (__hip_bfloat16*)args.out[z];
    #pragma unroll
    for (int m = 0; m < 2; ++m)
      #pragma unroll
      for (int n = 0; n < NREP; ++n) {
        const int cg = col0 + n * 16;   // F index -> row of vT
        const int rg = row0 + m * 16;   // asset index -> col of vT
        const float badd = bias[cg];
        ushort4 pk;
        pk.x = f2bf(acc[m][n][0] + badd);
        pk.y = f2bf(acc[m][n][1] + badd);
        pk.z = f2bf(acc[m][n][2] + badd);
        pk.w = f2bf(acc[m][n][3] + badd);
        *reinterpret_cast<ushort4*>(out + (size_t)cg * AD + rg) = pk;
      }
  }
}

// convert z, Wq, Wk (f32) -> bf16 into ws: [zb | Wqb | Wkb], 4M elems each
__global__ __launch_bounds__(256) void cvt_bf16(const float* __restrict__ z,
                                                const float* __restrict__ wq,
                                                const float* __restrict__ wk,
                                                __hip_bfloat16* __restrict__ dst) {
  const size_t NITEM = (size_t)3 * 4096 * 1024 / 8;
  const size_t step = (size_t)gridDim.x * blockDim.x;
  for (size_t idx = (size_t)blockIdx.x * blockDim.x + threadIdx.x; idx < NITEM; idx += step) {
    const int ten = (int)(idx >> 19);                 // 512K items per tensor
    const size_t off = (idx & ((1u << 19) - 1)) * 8;
    const float* src = (ten == 0) ? z : (ten == 1) ? wq : wk;
    const float4 a = *reinterpret_cast<const float4*>(src + off);
    const float4 b = *reinterpret_cast<const float4*>(src + off + 4);
    union { unsigned short us[8]; int4 v; } pk;
    pk.us[0] = f2bf(a.x); pk.us[1] = f2bf(a.y); pk.us[2] = f2bf(a.z); pk.us[3] = f2bf(a.w);
    pk.us[4] = f2bf(b.x); pk.us[5] = f2bf(b.y); pk.us[6] = f2bf(b.z); pk.us[7] = f2bf(b.w);
    *reinterpret_cast<int4*>(dst + (size_t)ten * 4096 * 1024 + off) = pk.v;
  }
}

__global__ __launch_bounds__(256) void softmax_rows(const float* __restrict__ S,
                                                    __hip_bfloat16* __restrict__ P) {
  const int row = blockIdx.x;
  const int t = threadIdx.x;
  const float* s = S + (size_t)row * AD + t * 8;
  const float4 v0 = *reinterpret_cast<const float4*>(s);
  const float4 v1 = *reinterpret_cast<const float4*>(s + 4);
  float vals[8] = {v0.x, v0.y, v0.z, v0.w, v1.x, v1.y, v1.z, v1.w};

  float m = vals[0];
  #pragma unroll
  for (int j = 1; j < 8; ++j) m = fmaxf(m, vals[j]);
  #pragma unroll
  for (int off = 32; off >= 1; off >>= 1) m = fmaxf(m, __shfl_xor(m, off));

  __shared__ float redm[4], reds[4];
  if ((t & 63) == 0) redm[t >> 6] = m;
  __syncthreads();
  m = fmaxf(fmaxf(redm[0], redm[1]), fmaxf(redm[2], redm[3]));

  float e[8];
  float sum = 0.f;
  #pragma unroll
  for (int j = 0; j < 8; ++j) { e[j] = __expf(vals[j] - m); sum += e[j]; }
  #pragma unroll
  for (int off = 32; off >= 1; off >>= 1) sum += __shfl_xor(sum, off);
  if ((t & 63) == 0) reds[t >> 6] = sum;
  __syncthreads();
  sum = reds[0] + reds[1] + reds[2] + reds[3];
  const float inv = 1.f / sum;

  union { unsigned short us[8]; int4 v; } pk;
  #pragma unroll
  for (int j = 0; j < 8; ++j) pk.us[j] = f2bf(e[j] * inv);
  *reinterpret_cast<int4*>(P + (size_t)row * AD + t * 8) = pk.v;
}

extern "C" void kernel_launch(void* const* d_in, const int* in_sizes, int n_in,
                              void* d_out, int out_size, void* d_ws, size_t ws_size,
                              hipStream_t stream) {
  const float* z  = (const float*)d_in[0];
  const float* Wq = (const float*)d_in[1];
  const float* bq = (const float*)d_in[2];
  const float* Wk = (const float*)d_in[3];
  const float* bk = (const float*)d_in[4];
  const float* Wv = (const float*)d_in[5];
  const float* bv = (const float*)d_in[6];

  char* ws = (char*)d_ws;
  const size_t MB8 = (size_t)8 * 1024 * 1024;
  __hip_bfloat16* zb  = (__hip_bfloat16*)(ws);            // dies after QKV
  __hip_bfloat16* Wqb = (__hip_bfloat16*)(ws + MB8);      // dies after QKV
  __hip_bfloat16* Wkb = (__hip_bfloat16*)(ws + 2*MB8);    // dies after QKV
  __hip_bfloat16* vT  = (__hip_bfloat16*)(ws + 3*MB8);    // live until PV
  float*          S   = (float*)(ws);                     // over zb+Wqb (16MB)
  __hip_bfloat16* P   = (__hip_bfloat16*)(ws + 2*MB8);    // over Wkb
  __hip_bfloat16* qb  = (__hip_bfloat16*)d_out;           // d_out scratch [0:8)MB
  __hip_bfloat16* kb  = (__hip_bfloat16*)d_out + (size_t)AD * FD;  // [8:16)MB

  // 0) convert z, Wq, Wk to bf16 (Wv consumed f32 in-kernel)
  cvt_bf16<<<dim3(2048), dim3(256), 0, stream>>>(z, Wq, Wk, (__hip_bfloat16*)ws);

  // 1) fused QKV: 768 blocks (~3/CU). z=0: q, z=1: k, z=2: v^T (B=Wv f32)
  {
    GemmArgs a;
    a.A = zb;
    a.B[0] = Wqb; a.B[1] = Wkb; a.B[2] = Wv;
    a.bias[0] = bq; a.bias[1] = bk; a.bias[2] = bv;
    a.out[0] = qb; a.out[1] = kb; a.out[2] = vT;
    a.outmode[0] = 1; a.outmode[1] = 1; a.outmode[2] = 2;
    a.bf32mask = 0b100;
    a.scale = 1.0f;
    gemm_k<4, -1, true><<<dim3(AD/128, AD/128, 3), dim3(512), 0, stream>>>(a);
  }
  // 2) scores = (qb @ kb^T)/8 -> f32 S ; 128x64 tiles, 512 blocks (~2/CU)
  {
    GemmArgs a = {};
    a.A = qb;
    a.B[0] = kb;
    a.bias[0] = nullptr;
    a.out[0] = S;
    a.outmode[0] = 0;
    a.bf32mask = 0;
    a.scale = SM_SCALE;
    gemm_k<2, 0, false><<<dim3(AD/64, AD/128, 1), dim3(512), 0, stream>>>(a);
  }
  // 3) row softmax -> P bf16
  softmax_rows<<<dim3(AD), dim3(256), 0, stream>>>(S, P);
  // 4) h = P @ vT^T -> f32 d_out ; 128x64 tiles, 512 blocks (~2/CU)
  {
    GemmArgs a = {};
    a.A = P;
    a.B[0] = vT;
    a.bias[0] = nullptr;
    a.out[0] = d_out;
    a.outmode[0] = 0;
    a.bf32mask = 0;
    a.scale = 1.0f;
    gemm_k<2, 0, false><<<dim3(AD/64, AD/128, 1), dim3(512), 0, stream>>>(a);
  }
}

// Round 5
// 162.555 us; speedup vs baseline: 1.5297x; 1.0174x over previous
//
#include <hip/hip_runtime.h>
#include <hip/hip_bf16.h>

// A=2048 assets, F=2048 flat dim.
//   q = z@Wq^T + bq ; k = z@Wk^T + bk ; v = z@Wv^T + bv
//   S = (q@k^T)/8 ; P = softmax_rows(S) ; h = P@v
// All GEMMs NT (A[m][k] . B[n][k]) on bf16 MFMA, f32 accum.
// v is produced transposed (vT) so PV is NT too.
// GEMM structure: double-buffered LDS, prefetch-next-then-compute, ONE
// barrier per K-step (T3 minimum-2-phase recipe).
//
// ws layout (32 MB), liveness:
//   [0:8)MB   zb   -> after QKV: S (f32, spans 0..16MB)
//   [8:16)MB  Wqb  ->           S cont'd
//   [16:24)MB Wkb  -> after scores: P (bf16)
//   [24:32)MB vT   (written by QKV z=2; live until PV)
//   d_out: qb[0:8)MB + kb[8:16)MB bf16 -> overwritten by final h (f32) in PV.
// Wv is consumed f32 directly (reg-stage+cvt on B side of z=2 blocks only).

#define AD 2048
#define FD 2048
constexpr float SM_SCALE = 0.125f;   // 64^-0.5

typedef __attribute__((ext_vector_type(8))) short bf16x8;
typedef __attribute__((ext_vector_type(4))) float f32x4;

__device__ __forceinline__ unsigned short f2bf(float f) {
  union { float f; unsigned u; } x; x.f = f;
  unsigned r = x.u + 0x7fffu + ((x.u >> 16) & 1u);   // RNE
  return (unsigned short)(r >> 16);
}

typedef __attribute__((address_space(1))) const void GVOID;
typedef __attribute__((address_space(3))) void LVOID;

__device__ __forceinline__ void gload16(const void* g, void* l) {
  __builtin_amdgcn_global_load_lds((GVOID*)g, (LVOID*)l, 16, 0, 0);
}

struct GemmArgs {
  const void* A;
  const void* B[3];
  const float* bias[3];
  void* out[3];
  int outmode[3];   // 0 = f32 row-major (xscale), 1 = bf16 row-major (+bias), 2 = bf16 C^T (+bias)
  int bf32mask;     // bit z: B[z] is f32 (reg-stage + cvt)
  float scale;
};

// BM=128 fixed, BK=32 fixed. BN = NREP*32. 512 threads = 8 waves (4 row x 2 col),
// wave tile = 32 x (NREP*16). FORCE_MODE >= 0 compiles a single epilogue.
template<int NREP, int FORCE_MODE, bool MIXEDB>
__global__ __launch_bounds__(512, 2) void gemm_k(GemmArgs args) {
  constexpr int BN_ = NREP * 32;
  __shared__ __hip_bfloat16 lA[2][128 * 32];
  __shared__ __hip_bfloat16 lB[2][BN_ * 32];

  const int z = blockIdx.z;
  const __hip_bfloat16* __restrict__ A = (const __hip_bfloat16*)args.A;

  const int t    = threadIdx.x;
  const int bn   = blockIdx.x, bm = blockIdx.y;
  const int lane = t & 63;
  const int wv   = t >> 6;
  const int wr   = wv >> 1;        // 0..3, 32 rows each
  const int wc   = wv & 1;         // 0..1, NREP*16 cols each

  const int srow = t >> 2;         // staging row (A: 0..127; B uses t < BN_*4)
  const int sce  = (t & 3) * 8;    // staging elem col
  const bool bstage = (BN_ == 128) || (t < BN_ * 4);

  const __hip_bfloat16* ga = A + (size_t)(bm * 128 + srow) * FD + sce;
  const __hip_bfloat16* gb = (const __hip_bfloat16*)args.B[z] + (size_t)(bn * BN_ + srow) * FD + sce;
  const float*          gf = (const float*)args.B[z] + (size_t)(bn * BN_ + srow) * FD + sce;

  bool dof32 = false;
  if constexpr (MIXEDB) dof32 = (args.bf32mask >> z) & 1;

  const int fr = lane & 15;
  const int ko = (lane >> 4) * 8;

  f32x4 acc[2][NREP] = {};

  // --- staging: issue tile k0 into buffer b ---
  auto STAGE = [&](int k0, int b) {
    gload16(ga + k0, &lA[b][t * 8]);
    if constexpr (MIXEDB) {
      if (dof32) {
        if (bstage) {
          const float4 x = *reinterpret_cast<const float4*>(gf + k0);
          const float4 y = *reinterpret_cast<const float4*>(gf + k0 + 4);
          union { unsigned short us[8]; int4 v; } pk;
          pk.us[0] = f2bf(x.x); pk.us[1] = f2bf(x.y); pk.us[2] = f2bf(x.z); pk.us[3] = f2bf(x.w);
          pk.us[4] = f2bf(y.x); pk.us[5] = f2bf(y.y); pk.us[6] = f2bf(y.z); pk.us[7] = f2bf(y.w);
          *reinterpret_cast<int4*>(&lB[b][t * 8]) = pk.v;
        }
      } else {
        if (bstage) gload16(gb + k0, &lB[b][t * 8]);
      }
    } else {
      if (bstage) gload16(gb + k0, &lB[b][t * 8]);
    }
  };

  // --- compute: frag reads + MFMA from buffer b ---
  auto COMPUTE = [&](int b) {
    bf16x8 af[2], bfr[NREP];
    #pragma unroll
    for (int m = 0; m < 2; ++m)
      af[m] = *reinterpret_cast<const bf16x8*>(&lA[b][(wr * 32 + m * 16 + fr) * 32 + ko]);
    #pragma unroll
    for (int n = 0; n < NREP; ++n)
      bfr[n] = *reinterpret_cast<const bf16x8*>(&lB[b][(wc * (NREP * 16) + n * 16 + fr) * 32 + ko]);
    #pragma unroll
    for (int m = 0; m < 2; ++m)
      #pragma unroll
      for (int n = 0; n < NREP; ++n)
        acc[m][n] = __builtin_amdgcn_mfma_f32_16x16x32_bf16(af[m], bfr[n], acc[m][n], 0, 0, 0);
  };

  // prologue
  STAGE(0, 0);
  __syncthreads();

  int cur = 0;
  for (int k0 = 32; k0 < FD; k0 += 32) {
    STAGE(k0, cur ^ 1);     // prefetch next tile: in flight during COMPUTE
    COMPUTE(cur);
    __syncthreads();        // drains vmcnt (prefetch) + all frag reads of cur
    cur ^= 1;
  }
  COMPUTE(cur);             // epilogue tile, no prefetch

  // C/D mapping (m89-verified): col = lane&15, row = (lane>>4)*4 + j
  const float scale = args.scale;
  const float* __restrict__ bias = args.bias[z];
  const int mode = (FORCE_MODE >= 0) ? FORCE_MODE : args.outmode[z];
  const int row0 = bm * 128 + wr * 32 + (lane >> 4) * 4;
  const int col0 = bn * BN_ + wc * (NREP * 16) + fr;

  if (mode == 0) {
    float* __restrict__ out = (float*)args.out[z];
    #pragma unroll
    for (int m = 0; m < 2; ++m)
      #pragma unroll
      for (int n = 0; n < NREP; ++n) {
        const int cg = col0 + n * 16;
        #pragma unroll
        for (int j = 0; j < 4; ++j)
          out[(size_t)(row0 + m * 16 + j) * FD + cg] = acc[m][n][j] * scale;
      }
  } else if (mode == 1) {
    __hip_bfloat16* __restrict__ out = (__hip_bfloat16*)args.out[z];
    #pragma unroll
    for (int m = 0; m < 2; ++m)
      #pragma unroll
      for (int n = 0; n < NREP; ++n) {
        const int cg = col0 + n * 16;
        const float badd = bias[cg];
        #pragma unroll
        for (int j = 0; j < 4; ++j) {
          unsigned short b16 = f2bf(acc[m][n][j] + badd);
          out[(size_t)(row0 + m * 16 + j) * FD + cg] = *reinterpret_cast<__hip_bfloat16*>(&b16);
        }
      }
  } else { // mode == 2: store C^T -> vT[f][a]; 4 consecutive rows pack to one 8B store
    __hip_bfloat16* __restrict__ out = (__hip_bfloat16*)args.out[z];
    #pragma unroll
    for (int m = 0; m < 2; ++m)
      #pragma unroll
      for (int n = 0; n < NREP; ++n) {
        const int cg = col0 + n * 16;   // F index -> row of vT
        const int rg = row0 + m * 16;   // asset index -> col of vT
        const float badd = bias[cg];
        ushort4 pk;
        pk.x = f2bf(acc[m][n][0] + badd);
        pk.y = f2bf(acc[m][n][1] + badd);
        pk.z = f2bf(acc[m][n][2] + badd);
        pk.w = f2bf(acc[m][n][3] + badd);
        *reinterpret_cast<ushort4*>(out + (size_t)cg * AD + rg) = pk;
      }
  }
}

// convert z, Wq, Wk (f32) -> bf16 into ws: [zb | Wqb | Wkb], 4M elems each
__global__ __launch_bounds__(256) void cvt_bf16(const float* __restrict__ z,
                                                const float* __restrict__ wq,
                                                const float* __restrict__ wk,
                                                __hip_bfloat16* __restrict__ dst) {
  const size_t NITEM = (size_t)3 * 4096 * 1024 / 8;
  const size_t step = (size_t)gridDim.x * blockDim.x;
  for (size_t idx = (size_t)blockIdx.x * blockDim.x + threadIdx.x; idx < NITEM; idx += step) {
    const int ten = (int)(idx >> 19);                 // 512K items per tensor
    const size_t off = (idx & ((1u << 19) - 1)) * 8;
    const float* src = (ten == 0) ? z : (ten == 1) ? wq : wk;
    const float4 a = *reinterpret_cast<const float4*>(src + off);
    const float4 b = *reinterpret_cast<const float4*>(src + off + 4);
    union { unsigned short us[8]; int4 v; } pk;
    pk.us[0] = f2bf(a.x); pk.us[1] = f2bf(a.y); pk.us[2] = f2bf(a.z); pk.us[3] = f2bf(a.w);
    pk.us[4] = f2bf(b.x); pk.us[5] = f2bf(b.y); pk.us[6] = f2bf(b.z); pk.us[7] = f2bf(b.w);
    *reinterpret_cast<int4*>(dst + (size_t)ten * 4096 * 1024 + off) = pk.v;
  }
}

__global__ __launch_bounds__(256) void softmax_rows(const float* __restrict__ S,
                                                    __hip_bfloat16* __restrict__ P) {
  const int row = blockIdx.x;
  const int t = threadIdx.x;
  const float* s = S + (size_t)row * AD + t * 8;
  const float4 v0 = *reinterpret_cast<const float4*>(s);
  const float4 v1 = *reinterpret_cast<const float4*>(s + 4);
  float vals[8] = {v0.x, v0.y, v0.z, v0.w, v1.x, v1.y, v1.z, v1.w};

  float m = vals[0];
  #pragma unroll
  for (int j = 1; j < 8; ++j) m = fmaxf(m, vals[j]);
  #pragma unroll
  for (int off = 32; off >= 1; off >>= 1) m = fmaxf(m, __shfl_xor(m, off));

  __shared__ float redm[4], reds[4];
  if ((t & 63) == 0) redm[t >> 6] = m;
  __syncthreads();
  m = fmaxf(fmaxf(redm[0], redm[1]), fmaxf(redm[2], redm[3]));

  float e[8];
  float sum = 0.f;
  #pragma unroll
  for (int j = 0; j < 8; ++j) { e[j] = __expf(vals[j] - m); sum += e[j]; }
  #pragma unroll
  for (int off = 32; off >= 1; off >>= 1) sum += __shfl_xor(sum, off);
  if ((t & 63) == 0) reds[t >> 6] = sum;
  __syncthreads();
  sum = reds[0] + reds[1] + reds[2] + reds[3];
  const float inv = 1.f / sum;

  union { unsigned short us[8]; int4 v; } pk;
  #pragma unroll
  for (int j = 0; j < 8; ++j) pk.us[j] = f2bf(e[j] * inv);
  *reinterpret_cast<int4*>(P + (size_t)row * AD + t * 8) = pk.v;
}

extern "C" void kernel_launch(void* const* d_in, const int* in_sizes, int n_in,
                              void* d_out, int out_size, void* d_ws, size_t ws_size,
                              hipStream_t stream) {
  const float* z  = (const float*)d_in[0];
  const float* Wq = (const float*)d_in[1];
  const float* bq = (const float*)d_in[2];
  const float* Wk = (const float*)d_in[3];
  const float* bk = (const float*)d_in[4];
  const float* Wv = (const float*)d_in[5];
  const float* bv = (const float*)d_in[6];

  char* ws = (char*)d_ws;
  const size_t MB8 = (size_t)8 * 1024 * 1024;
  __hip_bfloat16* zb  = (__hip_bfloat16*)(ws);            // dies after QKV
  __hip_bfloat16* Wqb = (__hip_bfloat16*)(ws + MB8);      // dies after QKV
  __hip_bfloat16* Wkb = (__hip_bfloat16*)(ws + 2*MB8);    // dies after QKV
  __hip_bfloat16* vT  = (__hip_bfloat16*)(ws + 3*MB8);    // live until PV
  float*          S   = (float*)(ws);                     // over zb+Wqb (16MB)
  __hip_bfloat16* P   = (__hip_bfloat16*)(ws + 2*MB8);    // over Wkb
  __hip_bfloat16* qb  = (__hip_bfloat16*)d_out;           // d_out scratch [0:8)MB
  __hip_bfloat16* kb  = (__hip_bfloat16*)d_out + (size_t)AD * FD;  // [8:16)MB

  // 0) convert z, Wq, Wk to bf16 (Wv consumed f32 in-kernel)
  cvt_bf16<<<dim3(2048), dim3(256), 0, stream>>>(z, Wq, Wk, (__hip_bfloat16*)ws);

  // 1) fused QKV: 768 blocks (~3/CU). z=0: q, z=1: k, z=2: v^T (B=Wv f32)
  {
    GemmArgs a;
    a.A = zb;
    a.B[0] = Wqb; a.B[1] = Wkb; a.B[2] = Wv;
    a.bias[0] = bq; a.bias[1] = bk; a.bias[2] = bv;
    a.out[0] = qb; a.out[1] = kb; a.out[2] = vT;
    a.outmode[0] = 1; a.outmode[1] = 1; a.outmode[2] = 2;
    a.bf32mask = 0b100;
    a.scale = 1.0f;
    gemm_k<4, -1, true><<<dim3(AD/128, AD/128, 3), dim3(512), 0, stream>>>(a);
  }
  // 2) scores = (qb @ kb^T)/8 -> f32 S ; 128x64 tiles, 512 blocks (~2/CU)
  {
    GemmArgs a = {};
    a.A = qb;
    a.B[0] = kb;
    a.bias[0] = nullptr;
    a.out[0] = S;
    a.outmode[0] = 0;
    a.bf32mask = 0;
    a.scale = SM_SCALE;
    gemm_k<2, 0, false><<<dim3(AD/64, AD/128, 1), dim3(512), 0, stream>>>(a);
  }
  // 3) row softmax -> P bf16
  softmax_rows<<<dim3(AD), dim3(256), 0, stream>>>(S, P);
  // 4) h = P @ vT^T -> f32 d_out ; 128x64 tiles, 512 blocks (~2/CU)
  {
    GemmArgs a = {};
    a.A = P;
    a.B[0] = vT;
    a.bias[0] = nullptr;
    a.out[0] = d_out;
    a.outmode[0] = 0;
    a.bf32mask = 0;
    a.scale = 1.0f;
    gemm_k<2, 0, false><<<dim3(AD/64, AD/128, 1), dim3(512), 0, stream>>>(a);
  }
}